// Round 2
// baseline (921.542 us; speedup 1.0000x reference)
//
#include <hip/hip_runtime.h>
#include <math.h>

// Problem constants (from reference)
#define NQ 32768   // query points (pos1)
#define MC 8192    // source points (pos2)
#define CC 128     // channels
#define EPS_BN 1e-5f
#define EPS_D  1e-8

#define DBLMAX 1e300

// ---------------------------------------------------------------------------
// KNN: each block = 64 queries x one half of M (4096 candidates).
// grid = (NQ/64)*2 blocks, 64 threads. Distances in fp64 so the top-3
// ordering is exact (matches the float64 numpy reference's selection).
// Outputs per (query, half): sorted ascending top-3 (d, idx).
// ---------------------------------------------------------------------------
__global__ __launch_bounds__(64) void knn_kernel(const float* __restrict__ pos1,
                                                 const float* __restrict__ pos2,
                                                 double* __restrict__ d6,
                                                 int* __restrict__ i6) {
    const int half = blockIdx.x & 1;
    const int n = (blockIdx.x >> 1) * 64 + threadIdx.x;

    __shared__ float4 sp[2048];   // x, y, z, unused (32 KB)
    __shared__ double s2d[2048];  // |p2|^2 in fp64 (16 KB)

    const double px = (double)pos1[n * 3 + 0];
    const double py = (double)pos1[n * 3 + 1];
    const double pz = (double)pos1[n * 3 + 2];
    const double s1 = px * px + py * py + pz * pz;
    const double m2x = -2.0 * px, m2y = -2.0 * py, m2z = -2.0 * pz;

    double d0 = DBLMAX, d1 = DBLMAX, d2 = DBLMAX;
    int i0 = 0, i1 = 0, i2 = 0;

    const int jbase = half * (MC / 2);
    for (int chunk = 0; chunk < 2; ++chunk) {
        const int cb = jbase + chunk * 2048;
        __syncthreads();
        for (int e = threadIdx.x; e < 2048; e += 64) {
            const int j = cb + e;
            float x = pos2[j * 3 + 0];
            float y = pos2[j * 3 + 1];
            float z = pos2[j * 3 + 2];
            sp[e] = make_float4(x, y, z, 0.f);
            const double xd = (double)x, yd = (double)y, zd = (double)z;
            s2d[e] = xd * xd + yd * yd + zd * zd;
        }
        __syncthreads();
#pragma unroll 4
        for (int e = 0; e < 2048; ++e) {
            const float4 c = sp[e];
            const double xd = (double)c.x, yd = (double)c.y, zd = (double)c.z;
            // d = |p1|^2 + |p2|^2 - 2*dot   (fp64: exact ordering)
            double d = fma(m2z, zd, fma(m2y, yd, fma(m2x, xd, s1 + s2d[e])));
            if (d < d2) {  // strict <  => lower index wins ties (top_k semantics)
                const int j = cb + e;
                if (d < d1) {
                    d2 = d1; i2 = i1;
                    if (d < d0) { d1 = d0; i1 = i0; d0 = d; i0 = j; }
                    else        { d1 = d;  i1 = j; }
                } else { d2 = d; i2 = j; }
            }
        }
    }
    const int o = (n * 2 + half) * 3;
    d6[o + 0] = d0; d6[o + 1] = d1; d6[o + 2] = d2;
    i6[o + 0] = i0; i6[o + 1] = i1; i6[o + 2] = i2;
}

// ---------------------------------------------------------------------------
// Merge the two sorted half-triples, compute inverse-distance weights (fp64).
// grid = NQ/256, 256 threads.
// ---------------------------------------------------------------------------
__global__ __launch_bounds__(256) void merge_kernel(const double* __restrict__ d6,
                                                    const int* __restrict__ i6,
                                                    int* __restrict__ idx3,
                                                    float* __restrict__ w3) {
    const int n = blockIdx.x * 256 + threadIdx.x;
    double da[6]; int ia[6];
#pragma unroll
    for (int k = 0; k < 6; ++k) { da[k] = d6[n * 6 + k]; ia[k] = i6[n * 6 + k]; }

    double dm[3]; int im[3];
    int a = 0, b = 3;
#pragma unroll
    for (int k = 0; k < 3; ++k) {
        bool takeB;
        if (a >= 3)      takeB = true;
        else if (b >= 6) takeB = false;
        else             takeB = (da[b] < da[a]);  // strict: tie -> half0 (lower idx)
        if (takeB) { dm[k] = da[b]; im[k] = ia[b]; ++b; }
        else       { dm[k] = da[a]; im[k] = ia[a]; ++a; }
    }

    const double r0 = 1.0 / (fmax(dm[0], 0.0) + EPS_D);
    const double r1 = 1.0 / (fmax(dm[1], 0.0) + EPS_D);
    const double r2 = 1.0 / (fmax(dm[2], 0.0) + EPS_D);
    const double inv = 1.0 / (r0 + r1 + r2);
    idx3[n * 3 + 0] = im[0]; idx3[n * 3 + 1] = im[1]; idx3[n * 3 + 2] = im[2];
    w3[n * 3 + 0] = (float)(r0 * inv);
    w3[n * 3 + 1] = (float)(r1 * inv);
    w3[n * 3 + 2] = (float)(r2 * inv);
}

// ---------------------------------------------------------------------------
// Interpolate: X[n][c] = sum_k w[n][k] * feat2[idx[n][k]][c]
// grid = NQ/2, 256 threads (2 points per block).
// ---------------------------------------------------------------------------
__global__ __launch_bounds__(256) void interp_kernel(const float* __restrict__ feat2,
                                                     const int* __restrict__ idx3,
                                                     const float* __restrict__ w3,
                                                     float* __restrict__ X) {
    const int n = blockIdx.x * 2 + (threadIdx.x >> 7);
    const int c = threadIdx.x & 127;
    const int i0 = idx3[n * 3 + 0], i1 = idx3[n * 3 + 1], i2 = idx3[n * 3 + 2];
    const float w0 = w3[n * 3 + 0], w1 = w3[n * 3 + 1], w2 = w3[n * 3 + 2];
    X[n * CC + c] = w0 * feat2[i0 * CC + c]
                  + w1 * feat2[i1 * CC + c]
                  + w2 * feat2[i2 * CC + c];
}

// ---------------------------------------------------------------------------
// fp32 GEMM: Y[n][co] = sum_ci X[n][ci] * W[co][ci] + bias[co]
// block tile 64 rows x 128 cols, 256 threads, micro-tile 8x4, K-chunks of 32.
// grid = NQ/64.
// ---------------------------------------------------------------------------
__global__ __launch_bounds__(256) void gemm_kernel(const float* __restrict__ X,
                                                   const float* __restrict__ W,
                                                   const float* __restrict__ bias,
                                                   float* __restrict__ Y) {
    __shared__ float xs[32][72];    // [kci][row], 288 B rows (16B aligned)
    __shared__ float wt[32][132];   // [kci][co],  528 B rows (16B aligned)

    const int row0 = blockIdx.x * 64;
    const int tx = threadIdx.x & 31;   // col group: cols tx*4 .. tx*4+3
    const int ty = threadIdx.x >> 5;   // row group: rows ty*8 .. ty*8+7

    float acc[8][4];
    {
        const float b0 = bias[tx * 4 + 0], b1 = bias[tx * 4 + 1];
        const float b2 = bias[tx * 4 + 2], b3 = bias[tx * 4 + 3];
#pragma unroll
        for (int r = 0; r < 8; ++r) { acc[r][0] = b0; acc[r][1] = b1; acc[r][2] = b2; acc[r][3] = b3; }
    }

    for (int kc = 0; kc < CC; kc += 32) {
        __syncthreads();
        // X tile: 64 rows x 32 k  (coalesced global read, transposed into LDS)
#pragma unroll
        for (int e = threadIdx.x; e < 64 * 32; e += 256) {
            const int r = e >> 5, j = e & 31;
            xs[j][r] = X[(row0 + r) * CC + kc + j];
        }
        // W tile: 128 co x 32 k
#pragma unroll
        for (int e = threadIdx.x; e < 128 * 32; e += 256) {
            const int co = e >> 5, j = e & 31;
            wt[j][co] = W[co * CC + kc + j];
        }
        __syncthreads();
#pragma unroll
        for (int j = 0; j < 32; ++j) {
            const float4 xv0 = *(const float4*)&xs[j][ty * 8 + 0];
            const float4 xv1 = *(const float4*)&xs[j][ty * 8 + 4];
            const float4 wv  = *(const float4*)&wt[j][tx * 4];
            const float xr[8] = {xv0.x, xv0.y, xv0.z, xv0.w, xv1.x, xv1.y, xv1.z, xv1.w};
            const float wc[4] = {wv.x, wv.y, wv.z, wv.w};
#pragma unroll
            for (int r = 0; r < 8; ++r)
#pragma unroll
                for (int c = 0; c < 4; ++c)
                    acc[r][c] = fmaf(xr[r], wc[c], acc[r][c]);
        }
    }
#pragma unroll
    for (int r = 0; r < 8; ++r) {
        float4 v = make_float4(acc[r][0], acc[r][1], acc[r][2], acc[r][3]);
        *(float4*)&Y[(row0 + ty * 8 + r) * CC + tx * 4] = v;
    }
}

// ---------------------------------------------------------------------------
// Column stats: sums[c] += sum_r Y[r][c], ss[c] += sum_r Y[r][c]^2
// grid = NQ/256 blocks x 128 threads.
// ---------------------------------------------------------------------------
__global__ __launch_bounds__(128) void stats_kernel(const float* __restrict__ Y,
                                                    float* __restrict__ sums,
                                                    float* __restrict__ ss) {
    const int c = threadIdx.x;
    const int r0 = blockIdx.x * 256;
    float s = 0.f, q = 0.f;
    for (int r = r0; r < r0 + 256; ++r) {
        const float v = Y[r * CC + c];
        s += v;
        q = fmaf(v, v, q);
    }
    atomicAdd(&sums[c], s);
    atomicAdd(&ss[c], q);
}

// ---------------------------------------------------------------------------
// BN (training batch stats, biased var) + ReLU, elementwise.
// grid = NQ*CC/256.
// ---------------------------------------------------------------------------
__global__ __launch_bounds__(256) void bn_relu_kernel(const float* __restrict__ Y,
                                                      const float* __restrict__ sums,
                                                      const float* __restrict__ ss,
                                                      const float* __restrict__ g,
                                                      const float* __restrict__ be,
                                                      float* __restrict__ Xout) {
    const int i = blockIdx.x * 256 + threadIdx.x;
    const int c = i & (CC - 1);
    const float m = sums[c] * (1.f / (float)NQ);
    const float v = ss[c] * (1.f / (float)NQ) - m * m;
    const float rstd = rsqrtf(v + EPS_BN);
    const float o = (Y[i] - m) * rstd * g[c] + be[c];
    Xout[i] = o > 0.f ? o : 0.f;
}

// ---------------------------------------------------------------------------
extern "C" void kernel_launch(void* const* d_in, const int* in_sizes, int n_in,
                              void* d_out, int out_size, void* d_ws, size_t ws_size,
                              hipStream_t stream) {
    (void)in_sizes; (void)n_in; (void)out_size; (void)ws_size;

    const float* pos1  = (const float*)d_in[0];
    const float* pos2  = (const float*)d_in[1];
    const float* feat2 = (const float*)d_in[2];
    const float* Wl[3]  = {(const float*)d_in[3], (const float*)d_in[7],  (const float*)d_in[11]};
    const float* bl[3]  = {(const float*)d_in[4], (const float*)d_in[8],  (const float*)d_in[12]};
    const float* gl[3]  = {(const float*)d_in[5], (const float*)d_in[9],  (const float*)d_in[13]};
    const float* bel[3] = {(const float*)d_in[6], (const float*)d_in[10], (const float*)d_in[14]};

    // Workspace layout
    float* ws = (float*)d_ws;
    float* A    = ws;                       // NQ*CC  (16 MB)
    float* B    = A + (size_t)NQ * CC;      // NQ*CC  (16 MB)
    double* d6  = (double*)(B + (size_t)NQ * CC);   // NQ*6 doubles (1.5 MB)
    int*   i6   = (int*)(d6 + (size_t)NQ * 6);      // NQ*6
    int*   idx3 = i6 + (size_t)NQ * 6;              // NQ*3
    float* w3   = (float*)(idx3 + (size_t)NQ * 3);  // NQ*3
    float* stats = w3 + (size_t)NQ * 3;     // 3 layers x (128 sums + 128 ss)

    hipMemsetAsync(stats, 0, 3 * 2 * CC * sizeof(float), stream);

    knn_kernel<<<(NQ / 64) * 2, 64, 0, stream>>>(pos1, pos2, d6, i6);
    merge_kernel<<<NQ / 256, 256, 0, stream>>>(d6, i6, idx3, w3);
    interp_kernel<<<NQ / 2, 256, 0, stream>>>(feat2, idx3, w3, A);

    float* out = (float*)d_out;
    for (int l = 0; l < 3; ++l) {
        float* sums = stats + l * 2 * CC;
        float* ssq  = sums + CC;
        gemm_kernel<<<NQ / 64, 256, 0, stream>>>(A, Wl[l], bl[l], B);
        stats_kernel<<<NQ / 256, 128, 0, stream>>>(B, sums, ssq);
        float* dst = (l == 2) ? out : A;
        bn_relu_kernel<<<(size_t)NQ * CC / 256, 256, 0, stream>>>(B, sums, ssq, gl[l], bel[l], dst);
    }
}

// Round 3
// 358.887 us; speedup vs baseline: 2.5678x; 2.5678x over previous
//
#include <hip/hip_runtime.h>
#include <math.h>

// Problem constants (from reference)
#define NQ 32768   // query points (pos1)
#define MC 8192    // source points (pos2)
#define CC 128     // channels
#define EPS_BN 1e-5f
#define EPS_D  1e-8

#define FLT_BIG 3.402823466e+38f
#define DBL_BIG 1e300
#define IDX_BIG 0x7fffffff

// KNN config
#define QB  64    // queries per block
#define TB  512   // threads per block (8 waves)
#define NW  8     // waves per block
#define CH  2048  // candidates staged per chunk
#define NCH (MC / CH)   // 4 chunks
#define SLC (CH / NW)   // per-chunk per-wave slice = 256

// ---------------------------------------------------------------------------
// KNN: block = 64 queries; 8 waves each scan a disjoint 1/8 of M in fp32
// (difference form: error ~3 ulp relative to d -> ~1e-8 abs for near pts),
// keeping a per-lane sorted top-4. The union of 8x4=32 candidates provably
// contains the true top-3. A fp64 refinement pass re-ranks the 32 exactly
// (matches the float64 numpy reference ordering) and computes the weights.
// Writes idx3 / w3 directly (no separate merge kernel).
// ---------------------------------------------------------------------------
__global__ __launch_bounds__(TB) void knn_kernel(const float* __restrict__ pos1,
                                                 const float* __restrict__ pos2,
                                                 int* __restrict__ idx3,
                                                 float* __restrict__ w3) {
    __shared__ float4 sp[CH];          // 32 KB staging: x,y,z,0
    __shared__ int    ridx[QB][NW * 4];   // 8 KB: surviving candidate indices
    __shared__ double rd[QB][NW * 4];     // 16 KB: refined fp64 distances

    const int wv = threadIdx.x >> 6;   // wave 0..7
    const int ln = threadIdx.x & 63;   // lane = query owner within block
    const int q  = blockIdx.x * QB + ln;

    const float px = pos1[q * 3 + 0];
    const float py = pos1[q * 3 + 1];
    const float pz = pos1[q * 3 + 2];

    float d0 = FLT_BIG, d1 = FLT_BIG, d2 = FLT_BIG, d3 = FLT_BIG;
    int   i0 = 0, i1 = 0, i2 = 0, i3 = 0;

    for (int c0 = 0; c0 < NCH; ++c0) {
        const int cb = c0 * CH;
        __syncthreads();
        {   // stage 4 points per thread: 3 coalesced float4 loads = 12 floats
            const int e0 = threadIdx.x * 4;
            const float4* g = (const float4*)(pos2 + (size_t)(cb + e0) * 3);
            const float4 f0 = g[0], f1 = g[1], f2 = g[2];
            sp[e0 + 0] = make_float4(f0.x, f0.y, f0.z, 0.f);
            sp[e0 + 1] = make_float4(f0.w, f1.x, f1.y, 0.f);
            sp[e0 + 2] = make_float4(f1.z, f1.w, f2.x, 0.f);
            sp[e0 + 3] = make_float4(f2.y, f2.z, f2.w, 0.f);
        }
        __syncthreads();
        const int sb = wv * SLC;
#pragma unroll 4
        for (int e = sb; e < sb + SLC; ++e) {
            const float4 c = sp[e];
            const float dx = px - c.x, dy = py - c.y, dz = pz - c.z;
            const float d = fmaf(dx, dx, fmaf(dy, dy, dz * dz));
            if (d < d3) {                    // rarely taken late in the scan
                const int j = cb + e;
                const bool c2 = d < d2, c1 = d < d1, cz = d < d0;
                d3 = c2 ? d2 : d;               i3 = c2 ? i2 : j;
                d2 = c2 ? (c1 ? d1 : d) : d2;   i2 = c2 ? (c1 ? i1 : j) : i2;
                d1 = c1 ? (cz ? d0 : d) : d1;   i1 = c1 ? (cz ? i0 : j) : i1;
                d0 = cz ? d : d0;               i0 = cz ? j : i0;
            }
        }
    }
    __syncthreads();
    ridx[ln][wv * 4 + 0] = i0;
    ridx[ln][wv * 4 + 1] = i1;
    ridx[ln][wv * 4 + 2] = i2;
    ridx[ln][wv * 4 + 3] = i3;
    __syncthreads();

    // R1: fp64 exact distances for all 32 survivors; 8 threads per query.
    {
        const int qq = threadIdx.x >> 3;       // 0..63
        const int g  = threadIdx.x & 7;        // slot group
        const int qglob = blockIdx.x * QB + qq;
        const double qx = (double)pos1[qglob * 3 + 0];
        const double qy = (double)pos1[qglob * 3 + 1];
        const double qz = (double)pos1[qglob * 3 + 2];
#pragma unroll
        for (int k = 0; k < 4; ++k) {
            const int s = g * 4 + k;
            const int id = ridx[qq][s];
            const double x = (double)pos2[id * 3 + 0];
            const double y = (double)pos2[id * 3 + 1];
            const double z = (double)pos2[id * 3 + 2];
            const double ax = qx - x, ay = qy - y, az = qz - z;
            rd[qq][s] = ax * ax + ay * ay + az * az;
        }
    }
    __syncthreads();

    // R2: wave 0 selects exact top-3 of the 32 (tie-break: lower index).
    if (threadIdx.x < QB) {
        const int qq = threadIdx.x;
        double b0 = DBL_BIG, b1 = DBL_BIG, b2 = DBL_BIG;
        int    j0 = IDX_BIG, j1 = IDX_BIG, j2 = IDX_BIG;
#pragma unroll
        for (int s = 0; s < NW * 4; ++s) {
            const double d = rd[qq][s];
            const int    id = ridx[qq][s];
            const bool l2 = (d < b2) || (d == b2 && id < j2);
            if (l2) {
                const bool l1 = (d < b1) || (d == b1 && id < j1);
                const bool l0 = (d < b0) || (d == b0 && id < j0);
                b2 = l1 ? b1 : d;              j2 = l1 ? j1 : id;
                b1 = l1 ? (l0 ? b0 : d) : b1;  j1 = l1 ? (l0 ? j0 : id) : j1;
                b0 = l0 ? d : b0;              j0 = l0 ? id : j0;
            }
        }
        const int qglob = blockIdx.x * QB + qq;
        const double r0 = 1.0 / (fmax(b0, 0.0) + EPS_D);
        const double r1 = 1.0 / (fmax(b1, 0.0) + EPS_D);
        const double r2 = 1.0 / (fmax(b2, 0.0) + EPS_D);
        const double inv = 1.0 / (r0 + r1 + r2);
        idx3[qglob * 3 + 0] = j0; idx3[qglob * 3 + 1] = j1; idx3[qglob * 3 + 2] = j2;
        w3[qglob * 3 + 0] = (float)(r0 * inv);
        w3[qglob * 3 + 1] = (float)(r1 * inv);
        w3[qglob * 3 + 2] = (float)(r2 * inv);
    }
}

// ---------------------------------------------------------------------------
// Interpolate: X[n][c] = sum_k w[n][k] * feat2[idx[n][k]][c]
// grid = NQ/2, 256 threads (2 points per block).
// ---------------------------------------------------------------------------
__global__ __launch_bounds__(256) void interp_kernel(const float* __restrict__ feat2,
                                                     const int* __restrict__ idx3,
                                                     const float* __restrict__ w3,
                                                     float* __restrict__ X) {
    const int n = blockIdx.x * 2 + (threadIdx.x >> 7);
    const int c = threadIdx.x & 127;
    const int i0 = idx3[n * 3 + 0], i1 = idx3[n * 3 + 1], i2 = idx3[n * 3 + 2];
    const float w0 = w3[n * 3 + 0], w1 = w3[n * 3 + 1], w2 = w3[n * 3 + 2];
    X[n * CC + c] = w0 * feat2[i0 * CC + c]
                  + w1 * feat2[i1 * CC + c]
                  + w2 * feat2[i2 * CC + c];
}

// ---------------------------------------------------------------------------
// fp32 GEMM: Y[n][co] = sum_ci X[n][ci] * W[co][ci] + bias[co]
// block tile 64 rows x 128 cols, 256 threads, micro-tile 8x4, K-chunks of 32.
// grid = NQ/64.
// ---------------------------------------------------------------------------
__global__ __launch_bounds__(256) void gemm_kernel(const float* __restrict__ X,
                                                   const float* __restrict__ W,
                                                   const float* __restrict__ bias,
                                                   float* __restrict__ Y) {
    __shared__ float xs[32][72];    // [kci][row], 288 B rows (16B aligned)
    __shared__ float wt[32][132];   // [kci][co],  528 B rows (16B aligned)

    const int row0 = blockIdx.x * 64;
    const int tx = threadIdx.x & 31;   // col group: cols tx*4 .. tx*4+3
    const int ty = threadIdx.x >> 5;   // row group: rows ty*8 .. ty*8+7

    float acc[8][4];
    {
        const float b0 = bias[tx * 4 + 0], b1 = bias[tx * 4 + 1];
        const float b2 = bias[tx * 4 + 2], b3 = bias[tx * 4 + 3];
#pragma unroll
        for (int r = 0; r < 8; ++r) { acc[r][0] = b0; acc[r][1] = b1; acc[r][2] = b2; acc[r][3] = b3; }
    }

    for (int kc = 0; kc < CC; kc += 32) {
        __syncthreads();
#pragma unroll
        for (int e = threadIdx.x; e < 64 * 32; e += 256) {
            const int r = e >> 5, j = e & 31;
            xs[j][r] = X[(row0 + r) * CC + kc + j];
        }
#pragma unroll
        for (int e = threadIdx.x; e < 128 * 32; e += 256) {
            const int co = e >> 5, j = e & 31;
            wt[j][co] = W[co * CC + kc + j];
        }
        __syncthreads();
#pragma unroll
        for (int j = 0; j < 32; ++j) {
            const float4 xv0 = *(const float4*)&xs[j][ty * 8 + 0];
            const float4 xv1 = *(const float4*)&xs[j][ty * 8 + 4];
            const float4 wv  = *(const float4*)&wt[j][tx * 4];
            const float xr[8] = {xv0.x, xv0.y, xv0.z, xv0.w, xv1.x, xv1.y, xv1.z, xv1.w};
            const float wc[4] = {wv.x, wv.y, wv.z, wv.w};
#pragma unroll
            for (int r = 0; r < 8; ++r)
#pragma unroll
                for (int c = 0; c < 4; ++c)
                    acc[r][c] = fmaf(xr[r], wc[c], acc[r][c]);
        }
    }
#pragma unroll
    for (int r = 0; r < 8; ++r) {
        float4 v = make_float4(acc[r][0], acc[r][1], acc[r][2], acc[r][3]);
        *(float4*)&Y[(row0 + ty * 8 + r) * CC + tx * 4] = v;
    }
}

// ---------------------------------------------------------------------------
// Column stats: sums[c] += sum_r Y[r][c], ss[c] += sum_r Y[r][c]^2
// grid = NQ/256 blocks x 128 threads.
// ---------------------------------------------------------------------------
__global__ __launch_bounds__(128) void stats_kernel(const float* __restrict__ Y,
                                                    float* __restrict__ sums,
                                                    float* __restrict__ ss) {
    const int c = threadIdx.x;
    const int r0 = blockIdx.x * 256;
    float s = 0.f, qq = 0.f;
    for (int r = r0; r < r0 + 256; ++r) {
        const float v = Y[r * CC + c];
        s += v;
        qq = fmaf(v, v, qq);
    }
    atomicAdd(&sums[c], s);
    atomicAdd(&ss[c], qq);
}

// ---------------------------------------------------------------------------
// BN (training batch stats, biased var) + ReLU, elementwise.
// grid = NQ*CC/256.
// ---------------------------------------------------------------------------
__global__ __launch_bounds__(256) void bn_relu_kernel(const float* __restrict__ Y,
                                                      const float* __restrict__ sums,
                                                      const float* __restrict__ ss,
                                                      const float* __restrict__ g,
                                                      const float* __restrict__ be,
                                                      float* __restrict__ Xout) {
    const int i = blockIdx.x * 256 + threadIdx.x;
    const int c = i & (CC - 1);
    const float m = sums[c] * (1.f / (float)NQ);
    const float v = ss[c] * (1.f / (float)NQ) - m * m;
    const float rstd = rsqrtf(v + EPS_BN);
    const float o = (Y[i] - m) * rstd * g[c] + be[c];
    Xout[i] = o > 0.f ? o : 0.f;
}

// ---------------------------------------------------------------------------
extern "C" void kernel_launch(void* const* d_in, const int* in_sizes, int n_in,
                              void* d_out, int out_size, void* d_ws, size_t ws_size,
                              hipStream_t stream) {
    (void)in_sizes; (void)n_in; (void)out_size; (void)ws_size;

    const float* pos1  = (const float*)d_in[0];
    const float* pos2  = (const float*)d_in[1];
    const float* feat2 = (const float*)d_in[2];
    const float* Wl[3]  = {(const float*)d_in[3], (const float*)d_in[7],  (const float*)d_in[11]};
    const float* bl[3]  = {(const float*)d_in[4], (const float*)d_in[8],  (const float*)d_in[12]};
    const float* gl[3]  = {(const float*)d_in[5], (const float*)d_in[9],  (const float*)d_in[13]};
    const float* bel[3] = {(const float*)d_in[6], (const float*)d_in[10], (const float*)d_in[14]};

    // Workspace layout (floats)
    float* ws = (float*)d_ws;
    float* A    = ws;                               // NQ*CC  (16 MB)
    float* B    = A + (size_t)NQ * CC;              // NQ*CC  (16 MB)
    int*   idx3 = (int*)(B + (size_t)NQ * CC);      // NQ*3
    float* w3   = (float*)(idx3 + (size_t)NQ * 3);  // NQ*3
    float* stats = w3 + (size_t)NQ * 3;             // 3 x (128 sums + 128 ss)

    hipMemsetAsync(stats, 0, 3 * 2 * CC * sizeof(float), stream);

    knn_kernel<<<NQ / QB, TB, 0, stream>>>(pos1, pos2, idx3, w3);
    interp_kernel<<<NQ / 2, 256, 0, stream>>>(feat2, idx3, w3, A);

    float* out = (float*)d_out;
    for (int l = 0; l < 3; ++l) {
        float* sums = stats + l * 2 * CC;
        float* ssq  = sums + CC;
        gemm_kernel<<<NQ / 64, 256, 0, stream>>>(A, Wl[l], bl[l], B);
        stats_kernel<<<NQ / 256, 128, 0, stream>>>(B, sums, ssq);
        float* dst = (l == 2) ? out : A;
        bn_relu_kernel<<<(size_t)NQ * CC / 256, 256, 0, stream>>>(B, sums, ssq, gl[l], bel[l], dst);
    }
}

// Round 4
// 352.515 us; speedup vs baseline: 2.6142x; 1.0181x over previous
//
#include <hip/hip_runtime.h>
#include <math.h>

// Problem constants (from reference)
#define NQ 32768   // query points (pos1)
#define MC 8192    // source points (pos2)
#define CC 128     // channels
#define EPS_BN 1e-5f
#define EPS_D  1e-8

#define DBL_BIG 1e300
#define IDX_BIG 0x7fffffff

// KNN config
#define QB  64          // queries per block (1 per lane)
#define TB  512         // threads per block (8 waves)
#define NW  8           // waves per block
#define CH  2048        // candidates staged per chunk
#define NCH (MC / CH)   // 4 chunks
#define SLC (CH / NW)   // per-chunk per-wave slice = 256
#define KMASK 0xFFFFE000u   // keep sign+exp+10 mantissa bits
#define IMASK 0x1FFFu       // 13-bit index (M=8192)

__device__ __forceinline__ unsigned umin_(unsigned a, unsigned b) { return a < b ? a : b; }
__device__ __forceinline__ unsigned umax_(unsigned a, unsigned b) { return a > b ? a : b; }

// ---------------------------------------------------------------------------
// KNN: block = 64 queries; 8 waves each scan a disjoint 1/8 of M.
// Candidate metric packed as a single sortable u32 key:
//   key = (bits(fp32 d) & 0xFFFFE000) | idx      (d >= 0 -> monotone as uint)
// Top-4 per lane kept with a BRANCHLESS 7-op v_min/v_max ladder (no cndmask
// chains, no divergent insert branch). The 8x4=32 survivors per query are
// re-ranked exactly in fp64 (matches the float64 numpy reference ordering,
// index tie-break); quantization error (2^-10 rel) is absorbed by the top-4
// guard and only ever swaps near-equidistant neighbors (weight shift ~1e-3).
// ---------------------------------------------------------------------------
__global__ __launch_bounds__(TB) void knn_kernel(const float* __restrict__ pos1,
                                                 const float* __restrict__ pos2,
                                                 int* __restrict__ idx3,
                                                 float* __restrict__ w3) {
    __shared__ float4 sp4[CH * 3 / 4];           // 24 KB packed xyzxyz...
    __shared__ unsigned skey[QB][NW * 4];        // 8 KB survivor keys

    const int wv = threadIdx.x >> 6;   // wave 0..7
    const int ln = threadIdx.x & 63;   // lane = query owner
    const int q  = blockIdx.x * QB + ln;

    const float px = pos1[q * 3 + 0];
    const float py = pos1[q * 3 + 1];
    const float pz = pos1[q * 3 + 2];

    unsigned k0 = 0xFFFFFFFFu, k1 = 0xFFFFFFFFu, k2 = 0xFFFFFFFFu, k3 = 0xFFFFFFFFu;

    for (int c0 = 0; c0 < NCH; ++c0) {
        const int cb = c0 * CH;
        __syncthreads();
        {   // stage 24 KB chunk, coalesced float4 copy
            const float4* g4 = (const float4*)(pos2 + (size_t)cb * 3);
#pragma unroll
            for (int i = threadIdx.x; i < CH * 3 / 4; i += TB) sp4[i] = g4[i];
        }
        __syncthreads();
        const float4* b4 = sp4 + wv * (SLC * 3 / 4);
        const int jb = cb + wv * SLC;
#pragma unroll 2
        for (int gi = 0; gi < SLC / 4; ++gi) {
            const float4 A = b4[gi * 3 + 0];
            const float4 B = b4[gi * 3 + 1];
            const float4 Cv = b4[gi * 3 + 2];
            const int j = jb + gi * 4;
            // 4 candidates: (A.x A.y A.z)(A.w B.x B.y)(B.z B.w Cv.x)(Cv.y Cv.z Cv.w)
            const float cx[4] = {A.x, A.w, B.z, Cv.y};
            const float cy[4] = {A.y, B.x, B.w, Cv.z};
            const float cz[4] = {A.z, B.y, Cv.x, Cv.w};
#pragma unroll
            for (int u = 0; u < 4; ++u) {
                const float dx = px - cx[u], dy = py - cy[u], dz = pz - cz[u];
                const float d = fmaf(dx, dx, fmaf(dy, dy, dz * dz));
                unsigned e = (__float_as_uint(d) & KMASK) | (unsigned)(j + u);
                unsigned t;
                t = umin_(k0, e); e = umax_(k0, e); k0 = t;
                t = umin_(k1, e); e = umax_(k1, e); k1 = t;
                t = umin_(k2, e); e = umax_(k2, e); k2 = t;
                k3 = umin_(k3, e);
            }
        }
    }
    skey[ln][wv * 4 + 0] = k0;
    skey[ln][wv * 4 + 1] = k1;
    skey[ln][wv * 4 + 2] = k2;
    skey[ln][wv * 4 + 3] = k3;
    __syncthreads();

    // fp64 exact re-rank of the 32 survivors; one thread per query (wave 0).
    if (threadIdx.x < QB) {
        const int qq = threadIdx.x;
        const int qg = blockIdx.x * QB + qq;
        const double qx = (double)pos1[qg * 3 + 0];
        const double qy = (double)pos1[qg * 3 + 1];
        const double qz = (double)pos1[qg * 3 + 2];
        double b0 = DBL_BIG, b1 = DBL_BIG, b2 = DBL_BIG;
        int    j0 = IDX_BIG, j1 = IDX_BIG, j2 = IDX_BIG;
#pragma unroll 4
        for (int s = 0; s < NW * 4; ++s) {
            const int id = (int)(skey[qq][s] & IMASK);
            const double x = (double)pos2[id * 3 + 0];
            const double y = (double)pos2[id * 3 + 1];
            const double z = (double)pos2[id * 3 + 2];
            const double ax = qx - x, ay = qy - y, az = qz - z;
            const double d = ax * ax + ay * ay + az * az;
            const bool l2 = (d < b2) || (d == b2 && id < j2);
            if (l2) {
                const bool l1 = (d < b1) || (d == b1 && id < j1);
                const bool l0 = (d < b0) || (d == b0 && id < j0);
                b2 = l1 ? b1 : d;              j2 = l1 ? j1 : id;
                b1 = l1 ? (l0 ? b0 : d) : b1;  j1 = l1 ? (l0 ? j0 : id) : j1;
                b0 = l0 ? d : b0;              j0 = l0 ? id : j0;
            }
        }
        const double r0 = 1.0 / (fmax(b0, 0.0) + EPS_D);
        const double r1 = 1.0 / (fmax(b1, 0.0) + EPS_D);
        const double r2 = 1.0 / (fmax(b2, 0.0) + EPS_D);
        const double inv = 1.0 / (r0 + r1 + r2);
        idx3[qg * 3 + 0] = j0; idx3[qg * 3 + 1] = j1; idx3[qg * 3 + 2] = j2;
        w3[qg * 3 + 0] = (float)(r0 * inv);
        w3[qg * 3 + 1] = (float)(r1 * inv);
        w3[qg * 3 + 2] = (float)(r2 * inv);
    }
}

// ---------------------------------------------------------------------------
// Fused layer GEMM: Y = Xin @ W^T + bias, with the input transform applied
// on-the-fly during X-tile staging and column stats accumulated on exit.
//   MODE 0: Xin = interp(feat2, idx3, w3)           (layer 0)
//   MODE 1: Xin = relu(BN(Yprev; sumsIn/ssqIn, g, be))  (layers 1, 2)
// Block: 256 threads, 64 rows x 128 cols, micro-tile 8x4, K-chunks of 32.
// grid = NQ/64. Epilogue: per-block column sum/sumsq -> LDS -> global atomics.
// ---------------------------------------------------------------------------
template <int MODE>
__global__ __launch_bounds__(256) void gemm_fused(const float* __restrict__ Xsrc,
                                                  const int* __restrict__ idx3,
                                                  const float* __restrict__ w3,
                                                  const float* __restrict__ sumsIn,
                                                  const float* __restrict__ ssqIn,
                                                  const float* __restrict__ gIn,
                                                  const float* __restrict__ beIn,
                                                  const float* __restrict__ W,
                                                  const float* __restrict__ bias,
                                                  float* __restrict__ Y,
                                                  float* __restrict__ sumsOut,
                                                  float* __restrict__ ssqOut) {
    __shared__ float xs[32][76];     // [k][row], 304 B rows (16B aligned, 4-way-max banks)
    __shared__ float wt[32][132];    // [k][co],  528 B rows
    __shared__ float lds_s[CC], lds_q[CC];

    const int row0 = blockIdx.x * 64;
    const int tx = threadIdx.x & 31;   // col group: cols tx*4..+3 ; also staging k-col
    const int ty = threadIdx.x >> 5;   // row group: rows ty*8..+7 ; also staging row base

    if (threadIdx.x < CC) { lds_s[threadIdx.x] = 0.f; lds_q[threadIdx.x] = 0.f; }

    float acc[8][4];
    {
        const float b0 = bias[tx * 4 + 0], b1 = bias[tx * 4 + 1];
        const float b2 = bias[tx * 4 + 2], b3 = bias[tx * 4 + 3];
#pragma unroll
        for (int r = 0; r < 8; ++r) { acc[r][0] = b0; acc[r][1] = b1; acc[r][2] = b2; acc[r][3] = b3; }
    }

    for (int kc = 0; kc < CC; kc += 32) {
        __syncthreads();
        // ---- X tile staging with fused input transform ----
        {
            const int c = kc + tx;   // this thread's staged column (fixed per chunk)
            float scale = 0.f, shift = 0.f;
            if (MODE == 1) {
                const float m  = sumsIn[c] * (1.f / (float)NQ);
                const float vv = fmaf(-m, m, ssqIn[c] * (1.f / (float)NQ));
                const float rstd = rsqrtf(vv + EPS_BN);
                scale = rstd * gIn[c];
                shift = fmaf(-m, scale, beIn[c]);
            }
#pragma unroll
            for (int rr = 0; rr < 8; ++rr) {
                const int r = ty + rr * 8;
                const int n = row0 + r;
                float val;
                if (MODE == 0) {
                    const int i0 = idx3[n * 3 + 0], i1 = idx3[n * 3 + 1], i2 = idx3[n * 3 + 2];
                    const float w0 = w3[n * 3 + 0], w1 = w3[n * 3 + 1], w2 = w3[n * 3 + 2];
                    val = w0 * Xsrc[(size_t)i0 * CC + c]
                        + w1 * Xsrc[(size_t)i1 * CC + c]
                        + w2 * Xsrc[(size_t)i2 * CC + c];
                } else {
                    val = fmaxf(fmaf(Xsrc[(size_t)n * CC + c], scale, shift), 0.f);
                }
                xs[tx][r] = val;
            }
        }
        // ---- W tile staging ----
#pragma unroll
        for (int e = threadIdx.x; e < 128 * 32; e += 256) {
            const int co = e >> 5, jj = e & 31;
            wt[jj][co] = W[co * CC + kc + jj];
        }
        __syncthreads();
        // ---- inner product ----
#pragma unroll
        for (int jj = 0; jj < 32; ++jj) {
            const float4 xv0 = *(const float4*)&xs[jj][ty * 8 + 0];
            const float4 xv1 = *(const float4*)&xs[jj][ty * 8 + 4];
            const float4 wv  = *(const float4*)&wt[jj][tx * 4];
            const float xr[8] = {xv0.x, xv0.y, xv0.z, xv0.w, xv1.x, xv1.y, xv1.z, xv1.w};
            const float wc[4] = {wv.x, wv.y, wv.z, wv.w};
#pragma unroll
            for (int r = 0; r < 8; ++r)
#pragma unroll
                for (int c = 0; c < 4; ++c)
                    acc[r][c] = fmaf(xr[r], wc[c], acc[r][c]);
        }
    }
    // ---- Y write ----
#pragma unroll
    for (int r = 0; r < 8; ++r) {
        const float4 v = make_float4(acc[r][0], acc[r][1], acc[r][2], acc[r][3]);
        *(float4*)&Y[(size_t)(row0 + ty * 8 + r) * CC + tx * 4] = v;
    }
    // ---- column stats epilogue ----
    float ps[4] = {0.f, 0.f, 0.f, 0.f}, pq[4] = {0.f, 0.f, 0.f, 0.f};
#pragma unroll
    for (int r = 0; r < 8; ++r)
#pragma unroll
        for (int c = 0; c < 4; ++c) {
            ps[c] += acc[r][c];
            pq[c] = fmaf(acc[r][c], acc[r][c], pq[c]);
        }
#pragma unroll
    for (int c = 0; c < 4; ++c) {
        atomicAdd(&lds_s[tx * 4 + c], ps[c]);
        atomicAdd(&lds_q[tx * 4 + c], pq[c]);
    }
    __syncthreads();
    if (threadIdx.x < CC) {
        atomicAdd(&sumsOut[threadIdx.x], lds_s[threadIdx.x]);
        atomicAdd(&ssqOut[threadIdx.x], lds_q[threadIdx.x]);
    }
}

// ---------------------------------------------------------------------------
// Final BN (training batch stats, biased var) + ReLU -> output.
// ---------------------------------------------------------------------------
__global__ __launch_bounds__(256) void bn_relu_kernel(const float* __restrict__ Y,
                                                      const float* __restrict__ sums,
                                                      const float* __restrict__ ss,
                                                      const float* __restrict__ g,
                                                      const float* __restrict__ be,
                                                      float* __restrict__ Xout) {
    const int i = blockIdx.x * 256 + threadIdx.x;
    const int c = i & (CC - 1);
    const float m = sums[c] * (1.f / (float)NQ);
    const float v = fmaf(-m, m, ss[c] * (1.f / (float)NQ));
    const float rstd = rsqrtf(v + EPS_BN);
    const float o = (Y[i] - m) * rstd * g[c] + be[c];
    Xout[i] = o > 0.f ? o : 0.f;
}

// ---------------------------------------------------------------------------
extern "C" void kernel_launch(void* const* d_in, const int* in_sizes, int n_in,
                              void* d_out, int out_size, void* d_ws, size_t ws_size,
                              hipStream_t stream) {
    (void)in_sizes; (void)n_in; (void)out_size; (void)ws_size;

    const float* pos1  = (const float*)d_in[0];
    const float* pos2  = (const float*)d_in[1];
    const float* feat2 = (const float*)d_in[2];
    const float* Wl[3]  = {(const float*)d_in[3], (const float*)d_in[7],  (const float*)d_in[11]};
    const float* bl[3]  = {(const float*)d_in[4], (const float*)d_in[8],  (const float*)d_in[12]};
    const float* gl[3]  = {(const float*)d_in[5], (const float*)d_in[9],  (const float*)d_in[13]};
    const float* bel[3] = {(const float*)d_in[6], (const float*)d_in[10], (const float*)d_in[14]};

    // Workspace layout (floats)
    float* ws = (float*)d_ws;
    float* B0   = ws;                               // NQ*CC (16 MB)
    float* B1   = B0 + (size_t)NQ * CC;             // NQ*CC (16 MB)
    int*   idx3 = (int*)(B1 + (size_t)NQ * CC);     // NQ*3
    float* w3   = (float*)(idx3 + (size_t)NQ * 3);  // NQ*3
    float* stats = w3 + (size_t)NQ * 3;             // 3 x (128 sums + 128 ssq)

    float* s0 = stats + 0 * 2 * CC; float* q0 = s0 + CC;
    float* s1 = stats + 1 * 2 * CC; float* q1 = s1 + CC;
    float* s2 = stats + 2 * 2 * CC; float* q2 = s2 + CC;

    hipMemsetAsync(stats, 0, 3 * 2 * CC * sizeof(float), stream);

    knn_kernel<<<NQ / QB, TB, 0, stream>>>(pos1, pos2, idx3, w3);

    // layer 0: interp fused into X load
    gemm_fused<0><<<NQ / 64, 256, 0, stream>>>(feat2, idx3, w3,
                                               nullptr, nullptr, nullptr, nullptr,
                                               Wl[0], bl[0], B0, s0, q0);
    // layer 1: BN(layer0)+ReLU fused into X load
    gemm_fused<1><<<NQ / 64, 256, 0, stream>>>(B0, nullptr, nullptr,
                                               s0, q0, gl[0], bel[0],
                                               Wl[1], bl[1], B1, s1, q1);
    // layer 2
    gemm_fused<1><<<NQ / 64, 256, 0, stream>>>(B1, nullptr, nullptr,
                                               s1, q1, gl[1], bel[1],
                                               Wl[2], bl[2], B0, s2, q2);
    // final BN+ReLU
    bn_relu_kernel<<<(size_t)NQ * CC / 256, 256, 0, stream>>>(B0, s2, q2, gl[2], bel[2],
                                                              (float*)d_out);
}

// Round 5
// 241.724 us; speedup vs baseline: 3.8124x; 1.4583x over previous
//
#include <hip/hip_runtime.h>
#include <math.h>

// Problem constants (from reference)
#define NQ 32768   // query points (pos1)
#define MC 8192    // source points (pos2)
#define CC 128     // channels
#define EPS_BN 1e-5f
#define EPS_D  1e-8

#define DBL_BIG 1e300
#define IDX_BIG 0x7fffffff

// KNN config
#define QB  64          // queries per block (1 per lane)
#define TB  512         // threads per block (8 waves)
#define NW  8           // waves per block
#define CH  2048        // candidates staged per chunk
#define NCH (MC / CH)   // 4 chunks
#define SLC (CH / NW)   // per-chunk per-wave slice = 256
#define KMASK 0xFFFFE000u   // keep sign+exp+10 mantissa bits
#define IMASK 0x1FFFu       // 13-bit index (M=8192)

typedef __attribute__((ext_vector_type(8))) short bf16x8;   // 8 bf16 (4 VGPRs)
typedef __attribute__((ext_vector_type(4))) float floatx4;  // MFMA accumulator

__device__ __forceinline__ unsigned umin_(unsigned a, unsigned b) { return a < b ? a : b; }
__device__ __forceinline__ unsigned umax_(unsigned a, unsigned b) { return a > b ? a : b; }

// RNE fp32 -> bf16 pair packed in u32 (lo = a, hi = b)
__device__ __forceinline__ unsigned bf16pair(float a, float b) {
    unsigned ua = __float_as_uint(a); ua = (ua + 0x7FFFu + ((ua >> 16) & 1u)) >> 16;
    unsigned ub = __float_as_uint(b); ub = (ub + 0x7FFFu + ((ub >> 16) & 1u)) >> 16;
    return ua | (ub << 16);
}

// ---------------------------------------------------------------------------
// KNN (unchanged from R4: VALU-issue-saturated at ~101 us).
// Sortable u32 key = (bits(d) & KMASK) | idx; branchless top-4 min/max ladder;
// fp64 exact re-rank of the 32 survivors (matches float64 numpy ordering).
// ---------------------------------------------------------------------------
__global__ __launch_bounds__(TB) void knn_kernel(const float* __restrict__ pos1,
                                                 const float* __restrict__ pos2,
                                                 int* __restrict__ idx3,
                                                 float* __restrict__ w3) {
    __shared__ float4 sp4[CH * 3 / 4];           // 24 KB packed xyzxyz...
    __shared__ unsigned skey[QB][NW * 4];        // 8 KB survivor keys

    const int wv = threadIdx.x >> 6;   // wave 0..7
    const int ln = threadIdx.x & 63;   // lane = query owner
    const int q  = blockIdx.x * QB + ln;

    const float px = pos1[q * 3 + 0];
    const float py = pos1[q * 3 + 1];
    const float pz = pos1[q * 3 + 2];

    unsigned k0 = 0xFFFFFFFFu, k1 = 0xFFFFFFFFu, k2 = 0xFFFFFFFFu, k3 = 0xFFFFFFFFu;

    for (int c0 = 0; c0 < NCH; ++c0) {
        const int cb = c0 * CH;
        __syncthreads();
        {
            const float4* g4 = (const float4*)(pos2 + (size_t)cb * 3);
#pragma unroll
            for (int i = threadIdx.x; i < CH * 3 / 4; i += TB) sp4[i] = g4[i];
        }
        __syncthreads();
        const float4* b4 = sp4 + wv * (SLC * 3 / 4);
        const int jb = cb + wv * SLC;
#pragma unroll 2
        for (int gi = 0; gi < SLC / 4; ++gi) {
            const float4 A = b4[gi * 3 + 0];
            const float4 B = b4[gi * 3 + 1];
            const float4 Cv = b4[gi * 3 + 2];
            const int j = jb + gi * 4;
            const float cx[4] = {A.x, A.w, B.z, Cv.y};
            const float cy[4] = {A.y, B.x, B.w, Cv.z};
            const float cz[4] = {A.z, B.y, Cv.x, Cv.w};
#pragma unroll
            for (int u = 0; u < 4; ++u) {
                const float dx = px - cx[u], dy = py - cy[u], dz = pz - cz[u];
                const float d = fmaf(dx, dx, fmaf(dy, dy, dz * dz));
                unsigned e = (__float_as_uint(d) & KMASK) | (unsigned)(j + u);
                unsigned t;
                t = umin_(k0, e); e = umax_(k0, e); k0 = t;
                t = umin_(k1, e); e = umax_(k1, e); k1 = t;
                t = umin_(k2, e); e = umax_(k2, e); k2 = t;
                k3 = umin_(k3, e);
            }
        }
    }
    skey[ln][wv * 4 + 0] = k0;
    skey[ln][wv * 4 + 1] = k1;
    skey[ln][wv * 4 + 2] = k2;
    skey[ln][wv * 4 + 3] = k3;
    __syncthreads();

    if (threadIdx.x < QB) {
        const int qq = threadIdx.x;
        const int qg = blockIdx.x * QB + qq;
        const double qx = (double)pos1[qg * 3 + 0];
        const double qy = (double)pos1[qg * 3 + 1];
        const double qz = (double)pos1[qg * 3 + 2];
        double b0 = DBL_BIG, b1 = DBL_BIG, b2 = DBL_BIG;
        int    j0 = IDX_BIG, j1 = IDX_BIG, j2 = IDX_BIG;
#pragma unroll 4
        for (int s = 0; s < NW * 4; ++s) {
            const int id = (int)(skey[qq][s] & IMASK);
            const double x = (double)pos2[id * 3 + 0];
            const double y = (double)pos2[id * 3 + 1];
            const double z = (double)pos2[id * 3 + 2];
            const double ax = qx - x, ay = qy - y, az = qz - z;
            const double d = ax * ax + ay * ay + az * az;
            const bool l2 = (d < b2) || (d == b2 && id < j2);
            if (l2) {
                const bool l1 = (d < b1) || (d == b1 && id < j1);
                const bool l0 = (d < b0) || (d == b0 && id < j0);
                b2 = l1 ? b1 : d;              j2 = l1 ? j1 : id;
                b1 = l1 ? (l0 ? b0 : d) : b1;  j1 = l1 ? (l0 ? j0 : id) : j1;
                b0 = l0 ? d : b0;              j0 = l0 ? id : j0;
            }
        }
        const double r0 = 1.0 / (fmax(b0, 0.0) + EPS_D);
        const double r1 = 1.0 / (fmax(b1, 0.0) + EPS_D);
        const double r2 = 1.0 / (fmax(b2, 0.0) + EPS_D);
        const double inv = 1.0 / (r0 + r1 + r2);
        idx3[qg * 3 + 0] = j0; idx3[qg * 3 + 1] = j1; idx3[qg * 3 + 2] = j2;
        w3[qg * 3 + 0] = (float)(r0 * inv);
        w3[qg * 3 + 1] = (float)(r1 * inv);
        w3[qg * 3 + 2] = (float)(r2 * inv);
    }
}

// ---------------------------------------------------------------------------
// bf16-MFMA fused layer GEMM: Y = Xin @ W^T + bias  (fp32 accumulate).
//   MODE 0: Xin = interp(feat2, idx3, w3)
//   MODE 1: Xin = relu(Xsrc * scale[c] + shift[c])   (BN of prev layer)
// Block: 256 threads / 4 waves; tile 64 rows x 128 cols; K=128 staged once
// in LDS as bf16 (ONE barrier pair). Wave w computes rows 16w..16w+15 via
// mfma_f32_16x16x32_bf16: A[m=lane&15][k=quad*8+j], B[n=lane&15][k=quad*8+j],
// D col=lane&15, row=quad*4+reg (verified layouts). Epilogue: bias add,
// column sum/sumsq via shfl_xor quad-reduce -> LDS -> per-block partials
// (NO contended global atomics). grid = NQ/64 = 512.
// ---------------------------------------------------------------------------
template <int MODE>
__global__ __launch_bounds__(256) void gemm_mfma(const float* __restrict__ Xsrc,
                                                 const int* __restrict__ idx3,
                                                 const float* __restrict__ w3,
                                                 const float* __restrict__ scale,
                                                 const float* __restrict__ shift,
                                                 const float* __restrict__ W,
                                                 const float* __restrict__ bias,
                                                 float* __restrict__ Y,
                                                 float* __restrict__ partials) {
    __shared__ short xa[64][136];    // 64 rows x 128 k bf16, stride 272 B (17x16B)
    __shared__ short wb[128][136];   // 128 co x 128 k bf16
    __shared__ float blk_s[CC], blk_q[CC];

    const int row0 = blockIdx.x * 64;

    if (threadIdx.x < CC) { blk_s[threadIdx.x] = 0.f; blk_q[threadIdx.x] = 0.f; }

    // ---- X tile staging (fused input transform), 8 iters of 256 threads ----
#pragma unroll
    for (int e = threadIdx.x; e < 64 * 32; e += 256) {
        const int r = e >> 5, c4 = e & 31;
        const int nrow = row0 + r;
        float4 v;
        if (MODE == 0) {
            const int i0 = idx3[nrow * 3 + 0], i1 = idx3[nrow * 3 + 1], i2 = idx3[nrow * 3 + 2];
            const float w0 = w3[nrow * 3 + 0], w1 = w3[nrow * 3 + 1], w2 = w3[nrow * 3 + 2];
            const float4 f0 = *(const float4*)&Xsrc[(size_t)i0 * CC + c4 * 4];
            const float4 f1 = *(const float4*)&Xsrc[(size_t)i1 * CC + c4 * 4];
            const float4 f2 = *(const float4*)&Xsrc[(size_t)i2 * CC + c4 * 4];
            v.x = w0 * f0.x + w1 * f1.x + w2 * f2.x;
            v.y = w0 * f0.y + w1 * f1.y + w2 * f2.y;
            v.z = w0 * f0.z + w1 * f1.z + w2 * f2.z;
            v.w = w0 * f0.w + w1 * f1.w + w2 * f2.w;
        } else {
            const float4 x  = *(const float4*)&Xsrc[(size_t)nrow * CC + c4 * 4];
            const float4 sc = *(const float4*)&scale[c4 * 4];
            const float4 sh = *(const float4*)&shift[c4 * 4];
            v.x = fmaxf(fmaf(x.x, sc.x, sh.x), 0.f);
            v.y = fmaxf(fmaf(x.y, sc.y, sh.y), 0.f);
            v.z = fmaxf(fmaf(x.z, sc.z, sh.z), 0.f);
            v.w = fmaxf(fmaf(x.w, sc.w, sh.w), 0.f);
        }
        unsigned* dst = (unsigned*)&xa[r][0];
        dst[c4 * 2 + 0] = bf16pair(v.x, v.y);
        dst[c4 * 2 + 1] = bf16pair(v.z, v.w);
    }
    // ---- W tile staging: full 128x128, 16 iters ----
#pragma unroll
    for (int e = threadIdx.x; e < 128 * 32; e += 256) {
        const int co = e >> 5, c4 = e & 31;
        const float4 wv4 = *(const float4*)&W[(size_t)co * CC + c4 * 4];
        unsigned* dst = (unsigned*)&wb[co][0];
        dst[c4 * 2 + 0] = bf16pair(wv4.x, wv4.y);
        dst[c4 * 2 + 1] = bf16pair(wv4.z, wv4.w);
    }
    __syncthreads();

    const int lane = threadIdx.x & 63;
    const int wv = threadIdx.x >> 6;     // wave -> rows 16*wv..+15
    const int nn = lane & 15;
    const int quad = lane >> 4;

    floatx4 acc[8] = {};   // 8 col-tiles x 4 fp32

    const short* arow = &xa[wv * 16 + nn][0];
#pragma unroll
    for (int ks = 0; ks < 4; ++ks) {
        const bf16x8 a = *(const bf16x8*)(arow + ks * 32 + quad * 8);
#pragma unroll
        for (int ct = 0; ct < 8; ++ct) {
            const bf16x8 b = *(const bf16x8*)(&wb[ct * 16 + nn][0] + ks * 32 + quad * 8);
            acc[ct] = __builtin_amdgcn_mfma_f32_16x16x32_bf16(a, b, acc[ct], 0, 0, 0);
        }
    }

    // ---- epilogue: bias, Y store, column stats ----
#pragma unroll
    for (int ct = 0; ct < 8; ++ct) {
        const float bv = bias[ct * 16 + nn];
        float s = 0.f, q = 0.f;
#pragma unroll
        for (int r = 0; r < 4; ++r) {
            acc[ct][r] += bv;
            s += acc[ct][r];
            q = fmaf(acc[ct][r], acc[ct][r], q);
        }
#pragma unroll
        for (int r = 0; r < 4; ++r)
            Y[(size_t)(row0 + wv * 16 + quad * 4 + r) * CC + ct * 16 + nn] = acc[ct][r];
        s += __shfl_xor(s, 16, 64); s += __shfl_xor(s, 32, 64);
        q += __shfl_xor(q, 16, 64); q += __shfl_xor(q, 32, 64);
        if (quad == 0) {
            atomicAdd(&blk_s[ct * 16 + nn], s);   // LDS atomics, 4 waves only
            atomicAdd(&blk_q[ct * 16 + nn], q);
        }
    }
    __syncthreads();
    if (threadIdx.x < CC) {
        partials[(size_t)blockIdx.x * 256 + threadIdx.x]       = blk_s[threadIdx.x];
        partials[(size_t)blockIdx.x * 256 + 128 + threadIdx.x] = blk_q[threadIdx.x];
    }
}

// ---------------------------------------------------------------------------
// Reduce per-block partials [512][256] -> BN scale/shift for the layer.
// 1 block x 1024 threads. scale = g*rsqrt(var+eps), shift = be - mean*scale.
// ---------------------------------------------------------------------------
__global__ __launch_bounds__(1024) void reduce_stats(const float* __restrict__ partials,
                                                     const float* __restrict__ g,
                                                     const float* __restrict__ be,
                                                     float* __restrict__ sc,
                                                     float* __restrict__ sh) {
    __shared__ float red[4][256];
    const int c = threadIdx.x & 255, seg = threadIdx.x >> 8;
    float s = 0.f;
    for (int b = seg * 128; b < seg * 128 + 128; ++b)
        s += partials[(size_t)b * 256 + c];
    red[seg][c] = s;
    __syncthreads();
    if (threadIdx.x < 256)
        red[0][c] = red[0][c] + red[1][c] + red[2][c] + red[3][c];
    __syncthreads();
    if (threadIdx.x < 128) {
        const float m = red[0][threadIdx.x] * (1.f / (float)NQ);
        const float v = fmaf(-m, m, red[0][threadIdx.x + 128] * (1.f / (float)NQ));
        const float rstd = rsqrtf(v + EPS_BN);
        const float scl = g[threadIdx.x] * rstd;
        sc[threadIdx.x] = scl;
        sh[threadIdx.x] = fmaf(-m, scl, be[threadIdx.x]);
    }
}

// ---------------------------------------------------------------------------
// Final BN + ReLU (vectorized float4). grid = NQ*CC/1024.
// ---------------------------------------------------------------------------
__global__ __launch_bounds__(256) void bn_relu_kernel(const float* __restrict__ Y,
                                                      const float* __restrict__ sc,
                                                      const float* __restrict__ sh,
                                                      float* __restrict__ out) {
    const int i4 = blockIdx.x * 256 + threadIdx.x;
    const int c4 = (i4 & 31) * 4;
    const float4 y = ((const float4*)Y)[i4];
    const float4 s = *(const float4*)&sc[c4];
    const float4 h = *(const float4*)&sh[c4];
    float4 o;
    o.x = fmaxf(fmaf(y.x, s.x, h.x), 0.f);
    o.y = fmaxf(fmaf(y.y, s.y, h.y), 0.f);
    o.z = fmaxf(fmaf(y.z, s.z, h.z), 0.f);
    o.w = fmaxf(fmaf(y.w, s.w, h.w), 0.f);
    ((float4*)out)[i4] = o;
}

// ---------------------------------------------------------------------------
extern "C" void kernel_launch(void* const* d_in, const int* in_sizes, int n_in,
                              void* d_out, int out_size, void* d_ws, size_t ws_size,
                              hipStream_t stream) {
    (void)in_sizes; (void)n_in; (void)out_size; (void)ws_size;

    const float* pos1  = (const float*)d_in[0];
    const float* pos2  = (const float*)d_in[1];
    const float* feat2 = (const float*)d_in[2];
    const float* Wl[3]  = {(const float*)d_in[3], (const float*)d_in[7],  (const float*)d_in[11]};
    const float* bl[3]  = {(const float*)d_in[4], (const float*)d_in[8],  (const float*)d_in[12]};
    const float* gl[3]  = {(const float*)d_in[5], (const float*)d_in[9],  (const float*)d_in[13]};
    const float* bel[3] = {(const float*)d_in[6], (const float*)d_in[10], (const float*)d_in[14]};

    // Workspace layout (floats)
    float* ws = (float*)d_ws;
    float* B0   = ws;                               // NQ*CC (16 MB)
    float* B1   = B0 + (size_t)NQ * CC;             // NQ*CC (16 MB)
    int*   idx3 = (int*)(B1 + (size_t)NQ * CC);     // NQ*3
    float* w3   = (float*)(idx3 + (size_t)NQ * 3);  // NQ*3
    float* part = w3 + (size_t)NQ * 3;              // 512*256 (512 KB)
    float* scsh = part + 512 * 256;                 // 3 layers x (sc128, sh128)

    float* sc0 = scsh + 0 * 256; float* sh0 = sc0 + CC;
    float* sc1 = scsh + 1 * 256; float* sh1 = sc1 + CC;
    float* sc2 = scsh + 2 * 256; float* sh2 = sc2 + CC;

    knn_kernel<<<NQ / QB, TB, 0, stream>>>(pos1, pos2, idx3, w3);

    // layer 0: interp fused
    gemm_mfma<0><<<NQ / 64, 256, 0, stream>>>(feat2, idx3, w3, nullptr, nullptr,
                                              Wl[0], bl[0], B0, part);
    reduce_stats<<<1, 1024, 0, stream>>>(part, gl[0], bel[0], sc0, sh0);
    // layer 1: BN(layer0)+ReLU fused
    gemm_mfma<1><<<NQ / 64, 256, 0, stream>>>(B0, nullptr, nullptr, sc0, sh0,
                                              Wl[1], bl[1], B1, part);
    reduce_stats<<<1, 1024, 0, stream>>>(part, gl[1], bel[1], sc1, sh1);
    // layer 2
    gemm_mfma<1><<<NQ / 64, 256, 0, stream>>>(B1, nullptr, nullptr, sc1, sh1,
                                              Wl[2], bl[2], B0, part);
    reduce_stats<<<1, 1024, 0, stream>>>(part, gl[2], bel[2], sc2, sh2);
    // final BN+ReLU
    bn_relu_kernel<<<(size_t)NQ * CC / 1024, 256, 0, stream>>>(B0, sc2, sh2, (float*)d_out);
}

// Round 6
// 231.691 us; speedup vs baseline: 3.9775x; 1.0433x over previous
//
#include <hip/hip_runtime.h>
#include <math.h>

// Problem constants (from reference)
#define NQ 32768   // query points (pos1)
#define MC 8192    // source points (pos2)
#define CC 128     // channels
#define EPS_BN 1e-5f
#define EPS_D  1e-8

#define DBL_BIG 1e300
#define IDX_BIG 0x7fffffff

// KNN config
#define QB  64          // queries per block (1 per lane)
#define TB  512         // threads per block (8 waves)
#define NW  8           // waves per block
#define CH  2048        // candidates staged per chunk
#define HM  (MC / 2)    // half of M per block = 4096
#define NCH (HM / CH)   // 2 chunks per block
#define SLC (CH / NW)   // per-chunk per-wave slice = 256
#define KMASK 0xFFFFE000u   // keep sign+exp+10 mantissa bits
#define IMASK 0x1FFFu       // 13-bit index (M=8192)
#define NSURV 64            // survivors per query (2 halves x 8 waves x 4)

typedef __attribute__((ext_vector_type(8))) short bf16x8;   // 8 bf16 (4 VGPRs)
typedef __attribute__((ext_vector_type(4))) float floatx4;  // MFMA accumulator
typedef unsigned short ushort_t;

__device__ __forceinline__ unsigned umin_(unsigned a, unsigned b) { return a < b ? a : b; }
__device__ __forceinline__ unsigned umax_(unsigned a, unsigned b) { return a > b ? a : b; }

// RNE fp32 -> bf16 pair packed in u32 (lo = a, hi = b)
__device__ __forceinline__ unsigned bf16pair(float a, float b) {
    unsigned ua = __float_as_uint(a); ua = (ua + 0x7FFFu + ((ua >> 16) & 1u)) >> 16;
    unsigned ub = __float_as_uint(b); ub = (ub + 0x7FFFu + ((ub >> 16) & 1u)) >> 16;
    return ua | (ub << 16);
}

// ---------------------------------------------------------------------------
// KNN scan: grid = (NQ/64) x 2 halves = 1024 blocks (4 blocks/CU, 100% occ).
// Block = 64 queries x half of M; 8 waves each scan 512 candidates.
// Sortable u32 key = (bits(fp32 d) & KMASK) | idx; branchless top-4 ladder.
// Per-query 32 survivor keys dumped to global (coalesced via LDS transpose);
// exact fp64 re-rank happens in rerank_kernel.
// ---------------------------------------------------------------------------
__global__ __launch_bounds__(TB) void knn_kernel(const float* __restrict__ pos1,
                                                 const float* __restrict__ pos2,
                                                 unsigned* __restrict__ skeys) {
    __shared__ float4 sp4[CH * 3 / 4];        // 24 KB packed xyzxyz...
    __shared__ unsigned skey[QB][NW * 4];     // 8 KB survivor keys

    const int half = blockIdx.x & 1;
    const int bq   = blockIdx.x >> 1;
    const int wv = threadIdx.x >> 6;   // wave 0..7
    const int ln = threadIdx.x & 63;   // lane = query owner
    const int q  = bq * QB + ln;

    const float px = pos1[q * 3 + 0];
    const float py = pos1[q * 3 + 1];
    const float pz = pos1[q * 3 + 2];

    unsigned k0 = 0xFFFFFFFFu, k1 = 0xFFFFFFFFu, k2 = 0xFFFFFFFFu, k3 = 0xFFFFFFFFu;

    for (int c0 = 0; c0 < NCH; ++c0) {
        const int cb = half * HM + c0 * CH;
        __syncthreads();
        {
            const float4* g4 = (const float4*)(pos2 + (size_t)cb * 3);
#pragma unroll
            for (int i = threadIdx.x; i < CH * 3 / 4; i += TB) sp4[i] = g4[i];
        }
        __syncthreads();
        const float4* b4 = sp4 + wv * (SLC * 3 / 4);
        const int jb = cb + wv * SLC;
#pragma unroll 2
        for (int gi = 0; gi < SLC / 4; ++gi) {
            const float4 A = b4[gi * 3 + 0];
            const float4 B = b4[gi * 3 + 1];
            const float4 Cv = b4[gi * 3 + 2];
            const int j = jb + gi * 4;
            const float cx[4] = {A.x, A.w, B.z, Cv.y};
            const float cy[4] = {A.y, B.x, B.w, Cv.z};
            const float cz[4] = {A.z, B.y, Cv.x, Cv.w};
#pragma unroll
            for (int u = 0; u < 4; ++u) {
                const float dx = px - cx[u], dy = py - cy[u], dz = pz - cz[u];
                const float d = fmaf(dx, dx, fmaf(dy, dy, dz * dz));
                unsigned e = (__float_as_uint(d) & KMASK) | (unsigned)(j + u);
                unsigned t;
                t = umin_(k0, e); e = umax_(k0, e); k0 = t;
                t = umin_(k1, e); e = umax_(k1, e); k1 = t;
                t = umin_(k2, e); e = umax_(k2, e); k2 = t;
                k3 = umin_(k3, e);
            }
        }
    }
    skey[ln][wv * 4 + 0] = k0;
    skey[ln][wv * 4 + 1] = k1;
    skey[ln][wv * 4 + 2] = k2;
    skey[ln][wv * 4 + 3] = k3;
    __syncthreads();

    // coalesced dump: 64 queries x 32 keys; survivor base = (q*2+half)*32
#pragma unroll
    for (int t = threadIdx.x * 4; t < threadIdx.x * 4 + 4; ++t) {
        const int ql = t >> 5, slot = t & 31;
        skeys[(size_t)((bq * QB + ql) * 2 + half) * 32 + slot] = skey[ql][slot];
    }
}

// ---------------------------------------------------------------------------
// Exact fp64 re-rank of the 64 survivors per query (matches the float64
// numpy reference ordering; index tie-break). One thread per query.
// grid = 128 x 256.
// ---------------------------------------------------------------------------
__global__ __launch_bounds__(256) void rerank_kernel(const float* __restrict__ pos1,
                                                     const float* __restrict__ pos2,
                                                     const unsigned* __restrict__ skeys,
                                                     int* __restrict__ idx3,
                                                     float* __restrict__ w3) {
    const int q = blockIdx.x * 256 + threadIdx.x;
    const double qx = (double)pos1[q * 3 + 0];
    const double qy = (double)pos1[q * 3 + 1];
    const double qz = (double)pos1[q * 3 + 2];
    double b0 = DBL_BIG, b1 = DBL_BIG, b2 = DBL_BIG;
    int    j0 = IDX_BIG, j1 = IDX_BIG, j2 = IDX_BIG;
    const uint4* kp = (const uint4*)(skeys + (size_t)q * NSURV);
#pragma unroll 4
    for (int g = 0; g < NSURV / 4; ++g) {
        const uint4 kk = kp[g];
        const unsigned ks[4] = {kk.x, kk.y, kk.z, kk.w};
#pragma unroll
        for (int u = 0; u < 4; ++u) {
            const int id = (int)(ks[u] & IMASK);
            const double x = (double)pos2[id * 3 + 0];
            const double y = (double)pos2[id * 3 + 1];
            const double z = (double)pos2[id * 3 + 2];
            const double ax = qx - x, ay = qy - y, az = qz - z;
            const double d = ax * ax + ay * ay + az * az;
            const bool l2 = (d < b2) || (d == b2 && id < j2);
            if (l2) {
                const bool l1 = (d < b1) || (d == b1 && id < j1);
                const bool l0 = (d < b0) || (d == b0 && id < j0);
                b2 = l1 ? b1 : d;              j2 = l1 ? j1 : id;
                b1 = l1 ? (l0 ? b0 : d) : b1;  j1 = l1 ? (l0 ? j0 : id) : j1;
                b0 = l0 ? d : b0;              j0 = l0 ? id : j0;
            }
        }
    }
    const double r0 = 1.0 / (fmax(b0, 0.0) + EPS_D);
    const double r1 = 1.0 / (fmax(b1, 0.0) + EPS_D);
    const double r2 = 1.0 / (fmax(b2, 0.0) + EPS_D);
    const double inv = 1.0 / (r0 + r1 + r2);
    idx3[q * 3 + 0] = j0; idx3[q * 3 + 1] = j1; idx3[q * 3 + 2] = j2;
    w3[q * 3 + 0] = (float)(r0 * inv);
    w3[q * 3 + 1] = (float)(r1 * inv);
    w3[q * 3 + 2] = (float)(r2 * inv);
}

// ---------------------------------------------------------------------------
// One-time weight conversion: fp32 W[co][k] -> bf16 (RNE), 3 layers.
// grid = 48 x 256 (16 blocks per layer, 4 elems/thread).
// ---------------------------------------------------------------------------
__global__ __launch_bounds__(256) void prep_w(const float* __restrict__ W0,
                                              const float* __restrict__ W1,
                                              const float* __restrict__ W2,
                                              ushort_t* __restrict__ out) {
    const int l = blockIdx.x >> 4;
    const int i4 = ((blockIdx.x & 15) * 256 + threadIdx.x) * 4;
    const float* W = (l == 0) ? W0 : ((l == 1) ? W1 : W2);
    const float4 v = *(const float4*)&W[i4];
    unsigned* dst = (unsigned*)(out + (size_t)l * CC * CC);
    dst[(i4 >> 1) + 0] = bf16pair(v.x, v.y);
    dst[(i4 >> 1) + 1] = bf16pair(v.z, v.w);
}

// ---------------------------------------------------------------------------
// bf16-MFMA fused layer GEMM: Y = Xin @ W^T + bias  (fp32 accumulate).
//   MODE 0: Xin = interp(feat2, idx3, w3)
//   MODE 1: Xin = relu(Xsrc * scale[c] + shift[c])   (BN of prev layer)
// W arrives pre-converted bf16 (prep_w) -> staging is pure 16B copies.
// Epilogue: bias, Y store, column sum/sumsq -> LDS -> channel-major partials
// partials[ch][block] (no contended global atomics). grid = NQ/64 = 512.
// ---------------------------------------------------------------------------
template <int MODE>
__global__ __launch_bounds__(256) void gemm_mfma(const float* __restrict__ Xsrc,
                                                 const int* __restrict__ idx3,
                                                 const float* __restrict__ w3,
                                                 const float* __restrict__ scale,
                                                 const float* __restrict__ shift,
                                                 const ushort_t* __restrict__ Wb,
                                                 const float* __restrict__ bias,
                                                 float* __restrict__ Y,
                                                 float* __restrict__ partials) {
    __shared__ short xa[64][136];    // 64 rows x 128 k bf16, stride 272 B
    __shared__ short wb[128][136];   // 128 co x 128 k bf16
    __shared__ float blk_s[CC], blk_q[CC];

    const int row0 = blockIdx.x * 64;

    if (threadIdx.x < CC) { blk_s[threadIdx.x] = 0.f; blk_q[threadIdx.x] = 0.f; }

    // ---- X tile staging (fused input transform), 8 iters ----
#pragma unroll
    for (int e = threadIdx.x; e < 64 * 32; e += 256) {
        const int r = e >> 5, c4 = e & 31;
        const int nrow = row0 + r;
        float4 v;
        if (MODE == 0) {
            const int i0 = idx3[nrow * 3 + 0], i1 = idx3[nrow * 3 + 1], i2 = idx3[nrow * 3 + 2];
            const float w0 = w3[nrow * 3 + 0], w1 = w3[nrow * 3 + 1], w2 = w3[nrow * 3 + 2];
            const float4 f0 = *(const float4*)&Xsrc[(size_t)i0 * CC + c4 * 4];
            const float4 f1 = *(const float4*)&Xsrc[(size_t)i1 * CC + c4 * 4];
            const float4 f2 = *(const float4*)&Xsrc[(size_t)i2 * CC + c4 * 4];
            v.x = w0 * f0.x + w1 * f1.x + w2 * f2.x;
            v.y = w0 * f0.y + w1 * f1.y + w2 * f2.y;
            v.z = w0 * f0.z + w1 * f1.z + w2 * f2.z;
            v.w = w0 * f0.w + w1 * f1.w + w2 * f2.w;
        } else {
            const float4 x  = *(const float4*)&Xsrc[(size_t)nrow * CC + c4 * 4];
            const float4 sc = *(const float4*)&scale[c4 * 4];
            const float4 sh = *(const float4*)&shift[c4 * 4];
            v.x = fmaxf(fmaf(x.x, sc.x, sh.x), 0.f);
            v.y = fmaxf(fmaf(x.y, sc.y, sh.y), 0.f);
            v.z = fmaxf(fmaf(x.z, sc.z, sh.z), 0.f);
            v.w = fmaxf(fmaf(x.w, sc.w, sh.w), 0.f);
        }
        unsigned* dst = (unsigned*)&xa[r][0];
        dst[c4 * 2 + 0] = bf16pair(v.x, v.y);
        dst[c4 * 2 + 1] = bf16pair(v.z, v.w);
    }
    // ---- W tile staging: pre-converted bf16, 16B copies, 8 iters ----
#pragma unroll
    for (int e = threadIdx.x; e < 128 * 16; e += 256) {
        const int co = e >> 4, seg = e & 15;
        *(float4*)&wb[co][seg * 8] = *(const float4*)&Wb[(size_t)co * CC + seg * 8];
    }
    __syncthreads();

    const int lane = threadIdx.x & 63;
    const int wv = threadIdx.x >> 6;     // wave -> rows 16*wv..+15
    const int nn = lane & 15;
    const int quad = lane >> 4;

    floatx4 acc[8] = {};   // 8 col-tiles x 4 fp32

    const short* arow = &xa[wv * 16 + nn][0];
#pragma unroll
    for (int ks = 0; ks < 4; ++ks) {
        const bf16x8 a = *(const bf16x8*)(arow + ks * 32 + quad * 8);
#pragma unroll
        for (int ct = 0; ct < 8; ++ct) {
            const bf16x8 b = *(const bf16x8*)(&wb[ct * 16 + nn][0] + ks * 32 + quad * 8);
            acc[ct] = __builtin_amdgcn_mfma_f32_16x16x32_bf16(a, b, acc[ct], 0, 0, 0);
        }
    }

    // ---- epilogue: bias, Y store, column stats ----
#pragma unroll
    for (int ct = 0; ct < 8; ++ct) {
        const float bv = bias[ct * 16 + nn];
        float s = 0.f, qv = 0.f;
#pragma unroll
        for (int r = 0; r < 4; ++r) {
            acc[ct][r] += bv;
            s += acc[ct][r];
            qv = fmaf(acc[ct][r], acc[ct][r], qv);
        }
#pragma unroll
        for (int r = 0; r < 4; ++r)
            Y[(size_t)(row0 + wv * 16 + quad * 4 + r) * CC + ct * 16 + nn] = acc[ct][r];
        s += __shfl_xor(s, 16, 64); s += __shfl_xor(s, 32, 64);
        qv += __shfl_xor(qv, 16, 64); qv += __shfl_xor(qv, 32, 64);
        if (quad == 0) {
            atomicAdd(&blk_s[ct * 16 + nn], s);
            atomicAdd(&blk_q[ct * 16 + nn], qv);
        }
    }
    __syncthreads();
    // channel-major partials: partials[ch][block], ch 0..127 = sum, 128..255 = ssq
    {
        const int ch = threadIdx.x;
        const float v = (ch < CC) ? blk_s[ch] : blk_q[ch - CC];
        partials[(size_t)ch * 512 + blockIdx.x] = v;
    }
}

// ---------------------------------------------------------------------------
// Reduce channel-major partials [256][512] -> BN scale/shift.
// grid = 128 blocks (one per channel) x 256 threads. ~4 KB per block.
// ---------------------------------------------------------------------------
__global__ __launch_bounds__(256) void reduce_stats(const float* __restrict__ P,
                                                    const float* __restrict__ g,
                                                    const float* __restrict__ be,
                                                    float* __restrict__ sc,
                                                    float* __restrict__ sh) {
    __shared__ float accS[4], accQ[4];
    const int c = blockIdx.x;
    const int t = threadIdx.x;
    float s  = P[(size_t)c * 512 + t]        + P[(size_t)c * 512 + 256 + t];
    float qv = P[(size_t)(c + CC) * 512 + t] + P[(size_t)(c + CC) * 512 + 256 + t];
#pragma unroll
    for (int off = 32; off >= 1; off >>= 1) {
        s  += __shfl_xor(s, off, 64);
        qv += __shfl_xor(qv, off, 64);
    }
    if ((t & 63) == 0) { accS[t >> 6] = s; accQ[t >> 6] = qv; }
    __syncthreads();
    if (t == 0) {
        const float S = accS[0] + accS[1] + accS[2] + accS[3];
        const float Q = accQ[0] + accQ[1] + accQ[2] + accQ[3];
        const float m = S * (1.f / (float)NQ);
        const float v = fmaf(-m, m, Q * (1.f / (float)NQ));
        const float rstd = rsqrtf(v + EPS_BN);
        const float scl = g[c] * rstd;
        sc[c] = scl;
        sh[c] = fmaf(-m, scl, be[c]);
    }
}

// ---------------------------------------------------------------------------
// Final BN + ReLU (vectorized float4). grid = NQ*CC/1024.
// ---------------------------------------------------------------------------
__global__ __launch_bounds__(256) void bn_relu_kernel(const float* __restrict__ Y,
                                                      const float* __restrict__ sc,
                                                      const float* __restrict__ sh,
                                                      float* __restrict__ out) {
    const int i4 = blockIdx.x * 256 + threadIdx.x;
    const int c4 = (i4 & 31) * 4;
    const float4 y = ((const float4*)Y)[i4];
    const float4 s = *(const float4*)&sc[c4];
    const float4 h = *(const float4*)&sh[c4];
    float4 o;
    o.x = fmaxf(fmaf(y.x, s.x, h.x), 0.f);
    o.y = fmaxf(fmaf(y.y, s.y, h.y), 0.f);
    o.z = fmaxf(fmaf(y.z, s.z, h.z), 0.f);
    o.w = fmaxf(fmaf(y.w, s.w, h.w), 0.f);
    ((float4*)out)[i4] = o;
}

// ---------------------------------------------------------------------------
extern "C" void kernel_launch(void* const* d_in, const int* in_sizes, int n_in,
                              void* d_out, int out_size, void* d_ws, size_t ws_size,
                              hipStream_t stream) {
    (void)in_sizes; (void)n_in; (void)out_size; (void)ws_size;

    const float* pos1  = (const float*)d_in[0];
    const float* pos2  = (const float*)d_in[1];
    const float* feat2 = (const float*)d_in[2];
    const float* Wl[3]  = {(const float*)d_in[3], (const float*)d_in[7],  (const float*)d_in[11]};
    const float* bl[3]  = {(const float*)d_in[4], (const float*)d_in[8],  (const float*)d_in[12]};
    const float* gl[3]  = {(const float*)d_in[5], (const float*)d_in[9],  (const float*)d_in[13]};
    const float* bel[3] = {(const float*)d_in[6], (const float*)d_in[10], (const float*)d_in[14]};

    // Workspace layout (floats). skeys aliases B1 (used only before gemm1).
    float* ws = (float*)d_ws;
    float* B0   = ws;                               // NQ*CC (16 MB)
    float* B1   = B0 + (size_t)NQ * CC;             // NQ*CC (16 MB)
    unsigned* skeys = (unsigned*)B1;                // NQ*64 u32 (8 MB, aliased)
    int*   idx3 = (int*)(B1 + (size_t)NQ * CC);     // NQ*3
    float* w3   = (float*)(idx3 + (size_t)NQ * 3);  // NQ*3
    float* part = w3 + (size_t)NQ * 3;              // 256*512 (512 KB)
    float* scsh = part + 256 * 512;                 // 3 layers x (sc128, sh128)
    ushort_t* Wbf = (ushort_t*)(scsh + 3 * 256);    // 3*16384 bf16 (96 KB)

    float* sc0 = scsh + 0 * 256; float* sh0 = sc0 + CC;
    float* sc1 = scsh + 1 * 256; float* sh1 = sc1 + CC;
    float* sc2 = scsh + 2 * 256; float* sh2 = sc2 + CC;

    prep_w<<<48, 256, 0, stream>>>(Wl[0], Wl[1], Wl[2], Wbf);
    knn_kernel<<<(NQ / QB) * 2, TB, 0, stream>>>(pos1, pos2, skeys);
    rerank_kernel<<<NQ / 256, 256, 0, stream>>>(pos1, pos2, skeys, idx3, w3);

    // layer 0: interp fused
    gemm_mfma<0><<<NQ / 64, 256, 0, stream>>>(feat2, idx3, w3, nullptr, nullptr,
                                              Wbf + 0 * CC * CC, bl[0], B0, part);
    reduce_stats<<<CC, 256, 0, stream>>>(part, gl[0], bel[0], sc0, sh0);
    // layer 1: BN(layer0)+ReLU fused  (overwrites skeys region — rerank done)
    gemm_mfma<1><<<NQ / 64, 256, 0, stream>>>(B0, nullptr, nullptr, sc0, sh0,
                                              Wbf + 1 * CC * CC, bl[1], B1, part);
    reduce_stats<<<CC, 256, 0, stream>>>(part, gl[1], bel[1], sc1, sh1);
    // layer 2
    gemm_mfma<1><<<NQ / 64, 256, 0, stream>>>(B1, nullptr, nullptr, sc1, sh1,
                                              Wbf + 2 * CC * CC, bl[2], B0, part);
    reduce_stats<<<CC, 256, 0, stream>>>(part, gl[2], bel[2], sc2, sh2);
    // final BN+ReLU
    bn_relu_kernel<<<(size_t)NQ * CC / 1024, 256, 0, stream>>>(B0, sc2, sh2, (float*)d_out);
}